// Round 4
// 265.728 us; speedup vs baseline: 1.1101x; 1.1101x over previous
//
#include <hip/hip_runtime.h>
#include <stdint.h>

// ================= problem constants =================
#define B_ATOMS 8192
#define C_CH    128
#define CHB     64     // channels per block (blockIdx.x in {0,1})
#define L_DIM   16
#define E_EL    10
#define NK3     23
#define NK2     4
#define NSLOT   1024   // GEMM K: 816 triples + 136 pairs + 16 singles + 56 pad
#define NCOL    32     // GEMM N: 23 k3 + 4 k2 + 1 k1 + 4 pad
#define ROWB    528    // A-tile row stride BYTES (132 dw, mod32=4 -> rows spread over banks)
#define TSE     72     // WT row stride, bf16 elems (36 dw)

// ---- LDS layout (bytes) ----
#define XX_OFF  0          // A chunk tile: 64 rows x 528 B = 33792
#define WT_OFF  33792      // bf16 [32][72]  = 4608 -> 38400
#define WS_OFF  38400      // f32 [4][64]    = 1024 -> 39424
#define SMEM_BYTES 39424   // 38.5 KB -> 4 blocks/CU

typedef __attribute__((ext_vector_type(8))) short short8;
typedef __attribute__((ext_vector_type(4))) float f32x4;

// ---- monomial slot table: k-slot -> (a,b,c); b/c==16 => factor 1, a==17 => zero pad ----
struct Lut3 { unsigned char a[NSLOT]; unsigned char b[NSLOT]; unsigned char c[NSLOT]; };
static constexpr Lut3 make_lut3() {
  Lut3 t{};
  int s = 0;
  for (int i = 0; i < 16; ++i)
    for (int j = i; j < 16; ++j)
      for (int k = j; k < 16; ++k) { t.a[s] = (unsigned char)i; t.b[s] = (unsigned char)j; t.c[s] = (unsigned char)k; ++s; }  // 816 triples
  for (int i = 0; i < 16; ++i)
    for (int j = i; j < 16; ++j) { t.a[s] = (unsigned char)i; t.b[s] = (unsigned char)j; t.c[s] = 16; ++s; }                  // 136 pairs
  for (int i = 0; i < 16; ++i) { t.a[s] = (unsigned char)i; t.b[s] = 16; t.c[s] = 16; ++s; }                                  // 16 singles
  for (; s < NSLOT; ++s) { t.a[s] = 17; t.b[s] = 17; t.c[s] = 17; }                                                           // pad -> 0
  return t;
}
__constant__ Lut3 LUT3C = make_lut3();          // runtime-indexed copy (build_bt)
static constexpr Lut3 LUT3 = make_lut3();       // compile-time copy (staging templates)

// ---- helpers ----
__device__ __forceinline__ unsigned short f2bf(float f) {            // RNE (setup kernel)
  union { float f; unsigned u; } v; v.f = f;
  unsigned r = v.u + 0x7fffu + ((v.u >> 16) & 1u);
  return (unsigned short)(r >> 16);
}
__device__ __forceinline__ unsigned pk_bf16(float lo, float hi) {    // RNE packed pair, 1 VALU
  unsigned r;
  asm("v_cvt_pk_bf16_f32 %0, %1, %2" : "=v"(r) : "v"(lo), "v"(hi));
  return r;
}
__device__ __forceinline__ float2 bfup(unsigned u) {                 // bf16 pair -> 2 f32
  float2 r;
  r.x = __uint_as_float(u << 16);
  r.y = __uint_as_float(u & 0xffff0000u);
  return r;
}
template <int CTRL>
__device__ __forceinline__ float dpp_add(float s) {
  int v = __builtin_amdgcn_update_dpp(0, __float_as_int(s), CTRL, 0xf, 0xf, true);
  return s + __int_as_float(v);
}
__device__ __forceinline__ float row16_sum(float s) {   // lane15 of each 16-row holds sum
  s = dpp_add<0x111>(s);
  s = dpp_add<0x112>(s);
  s = dpp_add<0x114>(s);
  s = dpp_add<0x118>(s);
  return s;
}

// ---- setup: fully-symmetrized monomial-basis B [32 cols][1024 k] bf16 ----
__global__ void build_bt(const float* __restrict__ U1, const float* __restrict__ U2,
                         const float* __restrict__ U3, unsigned short* __restrict__ bt) {
  int gid = blockIdx.x * 256 + threadIdx.x;
  if (gid >= NCOL * NSLOT) return;
  const int j  = gid >> 10;            // column 0..31
  const int kk = gid & (NSLOT - 1);    // k-slot
  const int a = LUT3C.a[kk], b = LUT3C.b[kk], c = LUT3C.c[kk];
  float val = 0.f;
  if (a < 16) {
    if (c < 16) {                      // triple {a<=b<=c}: sum U3 over distinct orderings
      if (j < NK3) {
        int P[6][3] = {{a,b,c},{a,c,b},{b,a,c},{b,c,a},{c,a,b},{c,b,a}};
        for (int t1 = 0; t1 < 6; ++t1) {
          bool dup = false;
          for (int t2 = 0; t2 < t1; ++t2)
            dup = dup || (P[t1][0]==P[t2][0] && P[t1][1]==P[t2][1] && P[t1][2]==P[t2][2]);
          if (!dup) val += U3[((P[t1][0]*16 + P[t1][1])*16 + P[t1][2])*NK3 + j];
        }
      }
    } else if (b < 16) {               // pair {a<=b}: symmetrized U2
      if (j >= NK3 && j < NK3 + NK2) {
        const int k2 = j - NK3;
        val = U2[(a*16 + b)*NK2 + k2];
        if (a != b) val += U2[(b*16 + a)*NK2 + k2];
      }
    } else {                           // single a
      if (j == NK3 + NK2) val = U1[a];
    }
  }
  bt[(size_t)gid] = f2bf(val);
}

// ---- monomial value for slot S (compile-time class dispatch; CSE shares pair products) ----
template <int S>
__device__ __forceinline__ float slot_val(const float* xf) {
  constexpr int a = LUT3.a[S], b = LUT3.b[S], c = LUT3.c[S];
  if constexpr (a >= 17) return 0.f;
  else if constexpr (b >= 16) return xf[a];
  else if constexpr (c >= 16) return xf[a] * xf[b];
  else return xf[a] * xf[b] * xf[c];
}

// ---- stage 64 slots (one wave's stripe of one chunk) as 8 ds_write_b128 ----
template <int S0, int G>
__device__ __forceinline__ void stage_groups(char* rb, const float* xf) {
  if constexpr (G < 8) {
    uint4 v;
    v.x = pk_bf16(slot_val<S0 + G*8 + 0>(xf), slot_val<S0 + G*8 + 1>(xf));
    v.y = pk_bf16(slot_val<S0 + G*8 + 2>(xf), slot_val<S0 + G*8 + 3>(xf));
    v.z = pk_bf16(slot_val<S0 + G*8 + 4>(xf), slot_val<S0 + G*8 + 5>(xf));
    v.w = pk_bf16(slot_val<S0 + G*8 + 6>(xf), slot_val<S0 + G*8 + 7>(xf));
    *(uint4*)(rb + G * 16) = v;
    stage_groups<S0, G + 1>(rb, xf);
  }
}

// ---- one K-chunk (256 slots): issue B loads, stage own stripe, 16 MFMA.
//      Wave w consumes ONLY slots its own lanes staged (stripe [128w,128w+128) of
//      every row), so no __syncthreads is needed: compiler fences pin the
//      ds_write -> ds_read -> (next) ds_write instruction order, and the LDS
//      pipeline executes a wave's DS ops in order. MFMAs are register-only and
//      may still sink past the fence to overlap next-chunk staging. ----
template <int T>
__device__ __forceinline__ void chunk_step(char* arow, const char* abase,
                                           const unsigned short* bp0,
                                           const unsigned short* bp1,
                                           const float* xf,
                                           f32x4 (&acc)[4][2], int wu) {
  // B frags for this chunk (global, L2-resident 64 KB): issue first, consume last
  short8 bfr[2][2];
#pragma unroll
  for (int e = 0; e < 2; ++e) {
    bfr[0][e] = *(const short8*)(bp0 + T * 256 + e * 32);
    bfr[1][e] = *(const short8*)(bp1 + T * 256 + e * 32);
  }
  switch (wu) {
    case 0:  stage_groups<T * 256 +   0, 0>(arow, xf); break;
    case 1:  stage_groups<T * 256 +  64, 0>(arow, xf); break;
    case 2:  stage_groups<T * 256 + 128, 0>(arow, xf); break;
    default: stage_groups<T * 256 + 192, 0>(arow, xf); break;
  }
  asm volatile("" ::: "memory");   // RAW: staging ds_writes precede af ds_reads
#pragma unroll
  for (int e = 0; e < 2; ++e) {
    short8 af[4];
#pragma unroll
    for (int mt = 0; mt < 4; ++mt)
      af[mt] = *(const short8*)(abase + mt * (16 * ROWB) + e * 64);
#pragma unroll
    for (int mt = 0; mt < 4; ++mt) {
      acc[mt][0] = __builtin_amdgcn_mfma_f32_16x16x32_bf16(af[mt], bfr[0][e], acc[mt][0], 0, 0, 0);
      acc[mt][1] = __builtin_amdgcn_mfma_f32_16x16x32_bf16(af[mt], bfr[1][e], acc[mt][1], 0, 0, 0);
    }
  }
  asm volatile("" ::: "memory");   // WAR: af ds_reads precede next chunk's staging writes
}

__global__ __launch_bounds__(256, 4) void mace_main(
    const float* __restrict__ x, const float* __restrict__ y,
    const float* __restrict__ W1, const float* __restrict__ W2,
    const float* __restrict__ W3,
    const unsigned short* __restrict__ bt, float* __restrict__ out) {
  __shared__ __align__(16) char smem[SMEM_BYTES];
  const int t    = threadIdx.x;
  const int b    = blockIdx.y;
  const int ch0  = blockIdx.x * CHB;
  const int lane = t & 63;
  const int wu   = __builtin_amdgcn_readfirstlane(t >> 6);   // wave id, forced uniform
  const int quad = lane >> 4, l16 = lane & 15;

  // ---- x: lane = channel; 16 f32 stay in registers for the whole kernel ----
  float xf[16];
  {
    const float4* xs = (const float4*)(x + ((size_t)b * C_CH + ch0 + lane) * L_DIM);
    float4 f0 = xs[0], f1 = xs[1], f2 = xs[2], f3 = xs[3];
    xf[0]=f0.x;  xf[1]=f0.y;  xf[2]=f0.z;  xf[3]=f0.w;
    xf[4]=f1.x;  xf[5]=f1.y;  xf[6]=f1.z;  xf[7]=f1.w;
    xf[8]=f2.x;  xf[9]=f2.y;  xf[10]=f2.z; xf[11]=f2.w;
    xf[12]=f3.x; xf[13]=f3.y; xf[14]=f3.z; xf[15]=f3.w;
  }

  // ---- WT: element-weighted W rows [32][64] bf16; rows 0..22 W3y, 23..26 W2y, 27 W1y, 28..31 zero ----
  {
    float yv[E_EL];
#pragma unroll
    for (int e = 0; e < E_EL; ++e) yv[e] = y[(size_t)b * E_EL + e];  // wave-uniform -> s_load
    unsigned short* wtb = (unsigned short*)(smem + WT_OFF);
#pragma unroll
    for (int u0 = 0; u0 < 2; ++u0) {
      const int u = t + u0 * 256;
      const int k = u >> 4, cg = (u & 15) * 4;
      float4 a = {0.f, 0.f, 0.f, 0.f};
      if (k < NK3) {
#pragma unroll
        for (int e = 0; e < E_EL; ++e) {
          float4 wv = *(const float4*)(W3 + ((size_t)e * NK3 + k) * C_CH + ch0 + cg);
          a.x += yv[e] * wv.x; a.y += yv[e] * wv.y; a.z += yv[e] * wv.z; a.w += yv[e] * wv.w;
        }
      } else if (k < NK3 + NK2) {
#pragma unroll
        for (int e = 0; e < E_EL; ++e) {
          float4 wv = *(const float4*)(W2 + ((size_t)e * NK2 + (k - NK3)) * C_CH + ch0 + cg);
          a.x += yv[e] * wv.x; a.y += yv[e] * wv.y; a.z += yv[e] * wv.z; a.w += yv[e] * wv.w;
        }
      } else if (k == NK3 + NK2) {
#pragma unroll
        for (int e = 0; e < E_EL; ++e) {
          float4 wv = *(const float4*)(W1 + (size_t)e * C_CH + ch0 + cg);
          a.x += yv[e] * wv.x; a.y += yv[e] * wv.y; a.z += yv[e] * wv.z; a.w += yv[e] * wv.w;
        }
      }
      uint2 pw;
      pw.x = pk_bf16(a.x, a.y);
      pw.y = pk_bf16(a.z, a.w);
      *(uint2*)(wtb + k * TSE + cg) = pw;
    }
  }
  __syncthreads();   // WT visible to all waves' epilogues

  // ---- barrier-free K-split GEMM over 4 chunks of 256 slots ----
  const unsigned short* const bp0 = bt + (l16 << 10) + wu * 64 + quad * 8;
  const unsigned short* const bp1 = bp0 + (16 << 10);
  char* const arow        = smem + XX_OFF + lane * ROWB + wu * 128;              // stage dst (own row, own stripe)
  const char* const abase = smem + XX_OFF + l16 * ROWB + wu * 128 + quad * 16;   // af src base
  f32x4 acc[4][2];
#pragma unroll
  for (int mt = 0; mt < 4; ++mt) {
    acc[mt][0] = (f32x4){0.f, 0.f, 0.f, 0.f};
    acc[mt][1] = (f32x4){0.f, 0.f, 0.f, 0.f};
  }
  chunk_step<0>(arow, abase, bp0, bp1, xf, acc, wu);
  chunk_step<1>(arow, abase, bp0, bp1, xf, acc, wu);
  chunk_step<2>(arow, abase, bp0, bp1, xf, acc, wu);
  chunk_step<3>(arow, abase, bp0, bp1, xf, acc, wu);

  // ---- epilogue: out[c] = sum_j T[c,j] * WT[j,c]; DPP-reduce over 16 cols per tile ----
  float* ws = (float*)(smem + WS_OFF);
  const unsigned short* wt = (const unsigned short*)(smem + WT_OFF);
#pragma unroll
  for (int mt = 0; mt < 4; ++mt) {
    const int c4 = mt * 16 + quad * 4;
    float s0 = 0.f, s1 = 0.f, s2 = 0.f, s3 = 0.f;
#pragma unroll
    for (int nt = 0; nt < 2; ++nt) {
      uint2 wv = *(const uint2*)(wt + (nt * 16 + l16) * TSE + c4);
      float2 w01 = bfup(wv.x), w23 = bfup(wv.y);
      s0 += acc[mt][nt][0] * w01.x;
      s1 += acc[mt][nt][1] * w01.y;
      s2 += acc[mt][nt][2] * w23.x;
      s3 += acc[mt][nt][3] * w23.y;
    }
    s0 = row16_sum(s0);
    s1 = row16_sum(s1);
    s2 = row16_sum(s2);
    s3 = row16_sum(s3);
    if (l16 == 15) *(float4*)(ws + wu * CHB + c4) = (float4){s0, s1, s2, s3};
  }
  __syncthreads();
  // ---- final: sum 4 wave K-partials, coalesced store ----
  if (t < CHB) {
    float s = ws[t] + ws[CHB + t] + ws[2 * CHB + t] + ws[3 * CHB + t];
    out[(size_t)b * C_CH + ch0 + t] = s;
  }
}

extern "C" void kernel_launch(void* const* d_in, const int* in_sizes, int n_in,
                              void* d_out, int out_size, void* d_ws, size_t ws_size,
                              hipStream_t stream) {
  const float* x  = (const float*)d_in[0];
  const float* y  = (const float*)d_in[1];
  const float* U1 = (const float*)d_in[2];
  const float* U2 = (const float*)d_in[3];
  const float* U3 = (const float*)d_in[4];
  const float* W1 = (const float*)d_in[5];
  const float* W2 = (const float*)d_in[6];
  const float* W3 = (const float*)d_in[7];
  float* out = (float*)d_out;
  unsigned short* bt = (unsigned short*)d_ws;
  if (ws_size < (size_t)NCOL * NSLOT * sizeof(unsigned short)) return;  // 65,536 B scratch

  build_bt<<<dim3((NCOL * NSLOT + 255) / 256), dim3(256), 0, stream>>>(U1, U2, U3, bt);
  mace_main<<<dim3(2, B_ATOMS), dim3(256), 0, stream>>>(x, y, W1, W2, W3, bt, out);
}